// Round 1
// baseline (50.705 us; speedup 1.0000x reference)
//
#include <hip/hip_runtime.h>
#include <stdint.h>

// Problem constants (match reference)
#define BB 8
#define SS 4096
#define TOKEN_BITS 12
#define EMB 1024
#define NB 12
#define TABLE 4096
#define POS_BITS 13

// ---------------------------------------------------------------------------
// Kernel 1: pack each neuron's 12 connection indices (each < 12, fits 4 bits)
// into one uint64 -> 8 KB table, so build_remap does a single 8B load/neuron.
// ---------------------------------------------------------------------------
__global__ void pack_conn(const int* __restrict__ conn, uint64_t* __restrict__ packed) {
    int n = blockIdx.x * blockDim.x + threadIdx.x;
    if (n < EMB) {
        uint64_t p = 0;
#pragma unroll
        for (int j = 0; j < NB; ++j)
            p |= (uint64_t)(conn[n * NB + j] & 0xF) << (4 * j);
        packed[n] = p;
    }
}

// ---------------------------------------------------------------------------
// Kernel 2: build remap[pattern][neuron-bit].
// For each of the 4096 possible 12-bit token patterns and each neuron:
//   addr = MSB-first pack of the connected pattern bits (same order as the
//          reference: addr = addr*2 + bit(connections[n][j]), j = 0..11)
//   bit  = tables[n][addr] != 0
// 64 consecutive-neuron lanes pack their bits with __ballot -> one uint64.
// Layout: remap_u64[pattern * 16 + n/64], bit (n & 63). 512 KB total.
// ---------------------------------------------------------------------------
__global__ __launch_bounds__(256) void build_remap(const float* __restrict__ tables,
                                                   const uint64_t* __restrict__ packed,
                                                   uint64_t* __restrict__ remap) {
    int tid = blockIdx.x * blockDim.x + threadIdx.x;  // 4096*1024 threads
    int n   = tid & (EMB - 1);                        // lanes = consecutive neurons
    int pat = tid >> 10;
    uint64_t pk = packed[n];
    int addr = 0;
#pragma unroll
    for (int j = 0; j < NB; ++j) {
        int c = (int)((pk >> (4 * j)) & 0xF);
        addr = (addr << 1) | ((pat >> c) & 1);        // j=0 is MSB, like reference
    }
    float v = tables[(size_t)n * TABLE + addr];
    uint64_t mask = __ballot(v != 0.0f);
    if ((threadIdx.x & 63) == 0)
        remap[(size_t)(tid >> 6)] = mask;             // = pat*16 + (n>>6)
}

// ---------------------------------------------------------------------------
// Kernel 3: main embedding. One block per (b,s). Thread 0 packs the 12 token
// bits into the pattern index; every thread then reads its 4 neuron bits from
// the 128 B remap row (L2-resident), XORs with the binary position encoding
// (pos bit k = (s >> (12 - (n % 13))) & 1), and writes one coalesced float4.
// ---------------------------------------------------------------------------
__global__ __launch_bounds__(256) void ram_embed(const int* __restrict__ tokens,
                                                 const uint32_t* __restrict__ remap,
                                                 float* __restrict__ out) {
    int bs = blockIdx.x;            // b*S + s
    int s  = bs & (SS - 1);

    __shared__ int s_tok;
    if (threadIdx.x == 0) {
        const int* tp = tokens + (size_t)bs * TOKEN_BITS;
        int t = 0;
#pragma unroll
        for (int j = 0; j < TOKEN_BITS; ++j) t |= (tp[j] & 1) << j;
        s_tok = t;
    }
    __syncthreads();

    int pat = s_tok;
    int t   = threadIdx.x;
    // word covers neurons 32*(t>>3) .. +31; our 4 bits start at (t&7)*4
    uint32_t word = remap[pat * (EMB / 32) + (t >> 3)];
    uint32_t nib  = (word >> ((t & 7) * 4)) & 0xFu;

    int n0 = t * 4;
    float o[4];
#pragma unroll
    for (int u = 0; u < 4; ++u) {
        int n    = n0 + u;
        int k    = n % POS_BITS;                 // which of the 13 pos bits
        int pbit = (s >> (POS_BITS - 1 - k)) & 1;
        int ebit = (int)(nib >> u) & 1;
        o[u] = (float)(ebit ^ pbit);
    }
    *reinterpret_cast<float4*>(out + (size_t)bs * EMB + n0) =
        make_float4(o[0], o[1], o[2], o[3]);
}

// ---------------------------------------------------------------------------
extern "C" void kernel_launch(void* const* d_in, const int* in_sizes, int n_in,
                              void* d_out, int out_size, void* d_ws, size_t ws_size,
                              hipStream_t stream) {
    const int*   tokens = (const int*)d_in[0];
    const float* tables = (const float*)d_in[1];
    const int*   conn   = (const int*)d_in[2];
    float*       out    = (float*)d_out;

    // ws layout: [0, 8KB) packed connections, [8KB, 8KB+512KB) remap bits
    uint64_t* packed = (uint64_t*)d_ws;
    uint64_t* remap  = packed + EMB;

    pack_conn<<<EMB / 256, 256, 0, stream>>>(conn, packed);
    build_remap<<<(TABLE * EMB) / 256, 256, 0, stream>>>(tables, packed, remap);
    ram_embed<<<BB * SS, 256, 0, stream>>>(tokens, (const uint32_t*)remap, out);
}

// Round 3
// 39.151 us; speedup vs baseline: 1.2951x; 1.2951x over previous
//
#include <hip/hip_runtime.h>
#include <stdint.h>

// Problem constants (match reference)
#define BB 8
#define SS 4096
#define TOKEN_BITS 12
#define EMB 1024
#define NB 12
#define TABLE 4096
#define POS_BITS 13
#define SPB 8   // sequence positions per block in ram_embed

typedef float f32x4 __attribute__((ext_vector_type(4)));

// ---------------------------------------------------------------------------
// Kernel 1: build remapT[n][pat-bits] — pattern-packed remap.
// One block per neuron: stage the 16 KB table row in LDS (coalesced float4
// global reads — the ONLY pass over the 16 MB table), then loop over all
// 4096 patterns; lanes = 64 consecutive patterns, __ballot packs a uint64.
// remapT64[n*64 + pat/64], bit (pat & 63). 512 KB total.
// ---------------------------------------------------------------------------
__global__ __launch_bounds__(256) void build_remapT(const float* __restrict__ tables,
                                                    const int* __restrict__ conn,
                                                    uint64_t* __restrict__ remapT) {
    __shared__ float row[TABLE];
    __shared__ int csh[NB];
    const int n = blockIdx.x;
    const int t = threadIdx.x;
    if (t < NB) csh[t] = conn[n * NB + t];
    const f32x4* src = (const f32x4*)(tables + (size_t)n * TABLE);
    f32x4* dst = (f32x4*)row;
#pragma unroll
    for (int i = 0; i < 4; ++i)
        dst[t + 256 * i] = src[t + 256 * i];
    __syncthreads();
    int cr[NB];
#pragma unroll
    for (int j = 0; j < NB; ++j) cr[j] = csh[j];
    for (int base = 0; base < TABLE; base += 256) {
        int pat = base + t;
        int addr = 0;
#pragma unroll
        for (int j = 0; j < NB; ++j)
            addr = (addr << 1) | ((pat >> cr[j]) & 1);   // j=0 is MSB (reference order)
        uint64_t m = __ballot(row[addr] != 0.0f);
        if ((t & 63) == 0)
            remapT[(size_t)n * (TABLE / 64) + (pat >> 6)] = m;
    }
}

// ---------------------------------------------------------------------------
// Kernel 2: bit-transpose remapT -> remap[pat][neuron-bits].
// Output word remap32[pat*32 + w] has bit i = neuron 32w+i.
// Block covers one w and 256 consecutive patterns: the 32 loads per thread
// are wave-broadcast (lanes share 1-2 words), everything is L2-resident.
// ---------------------------------------------------------------------------
__global__ __launch_bounds__(256) void transpose_remap(const uint32_t* __restrict__ remapT32,
                                                       uint32_t* __restrict__ remap32) {
    const int w   = blockIdx.x >> 4;                       // 0..31
    const int pat = ((blockIdx.x & 15) << 8) | threadIdx.x;
    const int wordIdx = pat >> 5;
    const int bit     = pat & 31;
    uint32_t res = 0;
#pragma unroll
    for (int i = 0; i < 32; ++i) {
        int n = 32 * w + i;
        res |= ((remapT32[(size_t)n * (TABLE / 32) + wordIdx] >> bit) & 1u) << i;
    }
    remap32[(size_t)pat * (EMB / 32) + w] = res;
}

// ---------------------------------------------------------------------------
// Kernel 3: main embedding. One block per SPB=8 consecutive (b,s) rows.
// Stage the 96 token ints in LDS, pack 8 pattern indices, then per row read
// the 128 B remap row (L2-hot) and emit one nontemporal float4 per thread.
// ---------------------------------------------------------------------------
__global__ __launch_bounds__(256) void ram_embed(const int* __restrict__ tokens,
                                                 const uint32_t* __restrict__ remap,
                                                 float* __restrict__ out) {
    const int g0 = blockIdx.x * SPB;            // first b*S+s row index
    const int t  = threadIdx.x;
    __shared__ int tok[SPB * TOKEN_BITS];
    __shared__ int pats[SPB];
    if (t < SPB * TOKEN_BITS)
        tok[t] = tokens[(size_t)g0 * TOKEN_BITS + t];
    __syncthreads();
    if (t < SPB) {
        int p = 0;
#pragma unroll
        for (int j = 0; j < TOKEN_BITS; ++j)
            p |= (tok[t * TOKEN_BITS + j] & 1) << j;
        pats[t] = p;
    }
    __syncthreads();

    const int n0 = t * 4;
    int sh[4];
#pragma unroll
    for (int u = 0; u < 4; ++u)
        sh[u] = POS_BITS - 1 - ((n0 + u) % POS_BITS);
    const int sbase = g0 & (SS - 1);            // SPB divides SS, so b is fixed

    for (int k = 0; k < SPB; ++k) {
        const int pat = pats[k];
        const int s   = sbase + k;
        uint32_t word = remap[(size_t)pat * (EMB / 32) + (t >> 3)];
        uint32_t nib  = (word >> ((t & 7) * 4)) & 0xFu;
        f32x4 o;
        o.x = (float)((int)((nib >> 0) & 1) ^ ((s >> sh[0]) & 1));
        o.y = (float)((int)((nib >> 1) & 1) ^ ((s >> sh[1]) & 1));
        o.z = (float)((int)((nib >> 2) & 1) ^ ((s >> sh[2]) & 1));
        o.w = (float)((int)((nib >> 3) & 1) ^ ((s >> sh[3]) & 1));
        __builtin_nontemporal_store(o, (f32x4*)(out + (size_t)(g0 + k) * EMB + n0));
    }
}

// ---------------------------------------------------------------------------
extern "C" void kernel_launch(void* const* d_in, const int* in_sizes, int n_in,
                              void* d_out, int out_size, void* d_ws, size_t ws_size,
                              hipStream_t stream) {
    const int*   tokens = (const int*)d_in[0];
    const float* tables = (const float*)d_in[1];
    const int*   conn   = (const int*)d_in[2];
    float*       out    = (float*)d_out;

    // ws layout: [0, 512KB) remapT (pattern-packed), [512KB, 1MB) remap (neuron-packed)
    uint64_t* remapT = (uint64_t*)d_ws;
    uint32_t* remap  = (uint32_t*)(remapT + EMB * (TABLE / 64));

    build_remapT<<<EMB, 256, 0, stream>>>(tables, conn, remapT);
    transpose_remap<<<(TABLE / 256) * (EMB / 32), 256, 0, stream>>>(
        (const uint32_t*)remapT, remap);
    ram_embed<<<BB * SS / SPB, 256, 0, stream>>>(tokens, remap, out);
}